// Round 1
// 915.462 us; speedup vs baseline: 1.1505x; 1.1505x over previous
//
#include <hip/hip_runtime.h>

typedef __attribute__((ext_vector_type(8))) short short8;
typedef __attribute__((ext_vector_type(4))) float floatx4;
typedef __attribute__((ext_vector_type(8))) int int8v;

__device__ __forceinline__ float bf2f(unsigned short u) {
    union { unsigned int i; float f; } c; c.i = ((unsigned int)u) << 16; return c.f;
}
__device__ __forceinline__ unsigned short f2bf(float f) {
    union { float f; unsigned int i; } c; c.f = f;
    unsigned int u = c.i;
    return (unsigned short)((u + 0x7FFFu + ((u >> 16) & 1u)) >> 16);
}
__device__ __forceinline__ unsigned short f2bf_rz(float f) {
    union { float f; unsigned int i; } c; c.f = f;
    return (unsigned short)(c.i >> 16);
}
__device__ __forceinline__ float sigm(float x) {
    return __builtin_amdgcn_rcpf(1.f + __expf(-x));
}
__device__ __forceinline__ float tanh_(float x) {
    return 1.f - 2.f * __builtin_amdgcn_rcpf(1.f + __expf(2.f * x));
}

__device__ __forceinline__ void glds16(const void* g, void* l) {
    __builtin_amdgcn_global_load_lds((const __attribute__((address_space(1))) unsigned int*)g,
                                     (__attribute__((address_space(3))) unsigned int*)l, 16, 0, 0);
}

// ---------------- cast weights to bf16 (w_ih_f | w_ih_b | w_fc) ----------------
__global__ void k_cast_weights(const float* __restrict__ wihf, const float* __restrict__ wihb,
                               const float* __restrict__ wfc, unsigned short* __restrict__ dst) {
    int i = blockIdx.x * 256 + threadIdx.x;
    if (i >= 532480) return;
    float v;
    if (i < 262144) v = wihf[i];
    else if (i < 524288) v = wihb[i - 262144];
    else v = wfc[i - 524288];
    dst[i] = f2bf(v);
}

// ---------------- cast w_hh (f|b) to fp8 e4m3 ----------------
__global__ void k_cast_fp8(const float* __restrict__ whhf, const float* __restrict__ whhb,
                           unsigned char* __restrict__ dst) {
    int i = blockIdx.x * 256 + threadIdx.x;   // 262144 threads, 2 elems each
    if (i >= 262144) return;
    int e = i * 2;
    float a = (e < 262144) ? whhf[e] : whhb[e - 262144];
    float b = (e + 1 < 262144) ? whhf[e + 1] : whhb[e + 1 - 262144];
    int p = __builtin_amdgcn_cvt_pk_fp8_f32(a, b, 0, false);
    *(unsigned short*)(dst + e) = (unsigned short)(p & 0xffff);
}

// ---------------- embedding gather -> e_t[t*64+b][256] bf16 ----------------
__global__ void k_gather(const int* __restrict__ x, const float* __restrict__ emb,
                         unsigned short* __restrict__ et) {
    int id = blockIdx.x * 256 + threadIdx.x;   // 1,048,576 total
    int m = id >> 5, fi = (id & 31) << 3;
    int b = m & 63, t = m >> 6;
    int v = x[b * 512 + t];
    const float4* s = (const float4*)(emb + ((size_t)v << 8) + fi);
    float4 a = s[0], q = s[1];
    uint4 o;
    o.x = (unsigned)f2bf(a.x) | ((unsigned)f2bf(a.y) << 16);
    o.y = (unsigned)f2bf(a.z) | ((unsigned)f2bf(a.w) << 16);
    o.z = (unsigned)f2bf(q.x) | ((unsigned)f2bf(q.y) << 16);
    o.w = (unsigned)f2bf(q.z) | ((unsigned)f2bf(q.w) << 16);
    *(uint4*)(et + ((size_t)m << 8) + fi) = o;
}

// ---------------- gx = e @ w_ih.T + b, both dirs (N=2048), output bf16 [d][t][b][1024] ----------------
__global__ __launch_bounds__(256, 2) void k_gx(const unsigned short* __restrict__ et,
                                               const unsigned short* __restrict__ wcat,
                                               const float* __restrict__ bfv, const float* __restrict__ bbv,
                                               unsigned short* __restrict__ gx) {
    __shared__ unsigned short As[4096];
    __shared__ unsigned short Bs[4096];
    const int tid = threadIdx.x;
    const int w = tid >> 6, l = tid & 63, quad = l >> 4, col = l & 15;
    const size_t m0 = (size_t)blockIdx.x * 128, n0 = (size_t)blockIdx.y * 128;
    floatx4 C[4][4];
    #pragma unroll
    for (int i = 0; i < 4; ++i)
        #pragma unroll
        for (int j = 0; j < 4; ++j) C[i][j] = (floatx4){0.f, 0.f, 0.f, 0.f};
    const int srow = tid >> 2, scol = (tid & 3) * 16;
    for (int it = 0; it < 8; ++it) {
        const char* ga = (const char*)et + (m0 + srow) * 512 + it * 64 + scol;
        const char* gb = (const char*)wcat + (n0 + srow) * 512 + it * 64 + scol;
        glds16(ga,             (char*)As + w * 1024);
        glds16(ga + 64 * 512,  (char*)As + 4096 + w * 1024);
        glds16(gb,             (char*)Bs + w * 1024);
        glds16(gb + 64 * 512,  (char*)Bs + 4096 + w * 1024);
        __syncthreads();
        short8 Af[4], Bf[4];
        #pragma unroll
        for (int i = 0; i < 4; ++i) {
            Af[i] = *(const short8*)(As + (((w & 1) * 64 + i * 16 + col) * 32 + quad * 8));
            Bf[i] = *(const short8*)(Bs + (((w >> 1) * 64 + i * 16 + col) * 32 + quad * 8));
        }
        #pragma unroll
        for (int i = 0; i < 4; ++i)
            #pragma unroll
            for (int j = 0; j < 4; ++j)
                C[i][j] = __builtin_amdgcn_mfma_f32_16x16x32_bf16(Af[i], Bf[j], C[i][j], 0, 0, 0);
        __syncthreads();
    }
    const int mw = (w & 1) * 64, nw = (w >> 1) * 64;
    #pragma unroll
    for (int j = 0; j < 4; ++j) {
        int n = (int)n0 + nw + j * 16 + col;
        float bias = (n < 1024) ? bfv[n] : bbv[n - 1024];
        size_t dbase = (size_t)(n >> 10) * 33554432 + (size_t)(n & 1023);
        #pragma unroll
        for (int i = 0; i < 4; ++i)
            #pragma unroll
            for (int r = 0; r < 4; ++r) {
                size_t m = m0 + mw + i * 16 + quad * 4 + r;
                gx[dbase + m * 1024] = f2bf(C[i][j][r] + bias);
            }
    }
}

// ---------------- LSTM recurrence: 64 wgs = 2 dirs x 32 batch-groups of 2; 512 thr (8 waves) ----
// Swapped-operand MFMA: A = h (fp8, rows alternate the 2 batches), B = W fragments.
// C[m][n] = z[batch = m&1][unit = n]  =>  every lane holds its own (batch,unit) z in-register:
//   z[g] = C[g][quad&1][quad>>1]  with  (b = l>>5, u = 32w + (l&31)).
// No zB LDS bounce, no gate-phase remap, ONE barrier per step (hld double-buffered).
__global__ __launch_bounds__(512, 2) void k_lstm(const unsigned char* __restrict__ w8_all,
                                                 const unsigned short* __restrict__ gx_all,
                                                 unsigned short* __restrict__ hcat) {
    const int d = blockIdx.x >> 5, bg = blockIdx.x & 31;
    const int tid = threadIdx.x, w = tid >> 6, l = tid & 63, quad = l >> 4, col = l & 15;
    const unsigned char* W = w8_all + (size_t)d * 262144;
    const unsigned short* G = gx_all + (size_t)d * 33554432;
    __shared__ __align__(32) unsigned char hld[2][2][288]; // 1,152 B  h fp8 [buf][batch][unit]

    // B-fragments (W): Wb[g][nt][kt] holds W[256g + 32w + 16nt + col][kt*128 + quad*32 .. +31]
    int8v Wb[4][2][2];
    #pragma unroll
    for (int g = 0; g < 4; ++g)
        #pragma unroll
        for (int nt = 0; nt < 2; ++nt)
            #pragma unroll
            for (int kt = 0; kt < 2; ++kt)
                Wb[g][nt][kt] = *(const int8v*)(W + (size_t)(256 * g + 32 * w + 16 * nt + col) * 256
                                                + kt * 128 + quad * 32);
    for (int i = tid; i < 288; i += 512) ((unsigned int*)hld)[i] = 0;

    const int b = l >> 5, u = 32 * w + (l & 31);           // this lane's (batch, unit)
    const int bglob = 2 * bg + b;
    const int nts = quad & 1, rs = quad >> 1;              // static-select coords for z extraction
    float cst = 0.f;
    const long gstep = d ? -65536 : 65536;                 // shorts per t in gx
    const long hstep = d ? -32768 : 32768;                 // shorts per t in hcat
    const unsigned short* gp = G + ((size_t)((d ? 511 : 0) * 64 + bglob) * 1024 + u);
    unsigned short* hp = hcat + ((size_t)((d ? 511 : 0) * 64 + bglob) * 512 + d * 256 + u);
    unsigned short gq0 = gp[0], gq1 = gp[256], gq2 = gp[512], gq3 = gp[768];
    gp += gstep;
    __syncthreads();

    #pragma clang loop unroll(disable)
    for (int step = 0; step < 512; ++step) {
        const int cur = step & 1;
        // ---- MFMA phase: A = h (lane row col -> batch col&1), B = W ----
        int8v Af[2];
        #pragma unroll
        for (int kt = 0; kt < 2; ++kt)
            Af[kt] = *(const int8v*)(&hld[cur][col & 1][kt * 128 + quad * 32]);
        floatx4 C[4][2];
        #pragma unroll
        for (int g = 0; g < 4; ++g)
            #pragma unroll
            for (int nt = 0; nt < 2; ++nt) C[g][nt] = (floatx4){0.f, 0.f, 0.f, 0.f};
        #pragma unroll
        for (int kt = 0; kt < 2; ++kt)
            #pragma unroll
            for (int g = 0; g < 4; ++g)
                #pragma unroll
                for (int nt = 0; nt < 2; ++nt)
                    C[g][nt] = __builtin_amdgcn_mfma_scale_f32_16x16x128_f8f6f4(
                        Af[kt], Wb[g][nt][kt], C[g][nt], 0, 0, 0, 0x7f7f7f7f, 0, 0x7f7f7f7f);
        // ---- in-register z extraction (static indices only; 3 cndmask per gate) ----
        float t0, t1, z0, z1, z2, z3;
        t0 = nts ? C[0][1][0] : C[0][0][0];
        t1 = nts ? C[0][1][1] : C[0][0][1];
        z0 = rs ? t1 : t0;
        t0 = nts ? C[1][1][0] : C[1][0][0];
        t1 = nts ? C[1][1][1] : C[1][0][1];
        z1 = rs ? t1 : t0;
        t0 = nts ? C[2][1][0] : C[2][0][0];
        t1 = nts ? C[2][1][1] : C[2][0][1];
        z2 = rs ? t1 : t0;
        t0 = nts ? C[3][1][0] : C[3][0][0];
        t1 = nts ? C[3][1][1] : C[3][0][1];
        z3 = rs ? t1 : t0;
        // ---- gate phase: fully distributed, one (batch,unit) per lane ----
        float vi = z0 + bf2f(gq0);
        float vf = z1 + bf2f(gq1);
        float vg = z2 + bf2f(gq2);
        float vo = z3 + bf2f(gq3);
        // prefetch next step's gx (in flight across barrier + next MFMA phase)
        gq0 = gp[0]; gq1 = gp[256]; gq2 = gp[512]; gq3 = gp[768];
        gp += gstep;
        float cc = sigm(vf) * cst + sigm(vi) * tanh_(vg);
        cst = cc;
        float hf = sigm(vo) * tanh_(cc);
        *hp = f2bf_rz(hf);
        hp += hstep;
        int pk = __builtin_amdgcn_cvt_pk_fp8_f32(hf, hf, 0, false);
        hld[cur ^ 1][b][u] = (unsigned char)(pk & 0xff);
        __syncthreads();
    }
}

// ---------------- scores = hcat @ w_fc.T + b_fc, fp32 [t][b][32] ----------------
__global__ __launch_bounds__(256, 4) void k_scores(const unsigned short* __restrict__ hcat,
                                                   const unsigned short* __restrict__ wfc,
                                                   const float* __restrict__ bfc,
                                                   float* __restrict__ sc) {
    const int tid = threadIdx.x, w = tid >> 6, l = tid & 63, quad = l >> 4, col = l & 15;
    const int m0 = blockIdx.x * 64 + w * 16;
    floatx4 C0 = (floatx4){0.f, 0.f, 0.f, 0.f}, C1 = C0;
    #pragma unroll
    for (int kt = 0; kt < 16; ++kt) {
        short8 A  = *(const short8*)(hcat + (size_t)(m0 + col) * 512 + kt * 32 + quad * 8);
        short8 B0 = *(const short8*)(wfc + (size_t)col * 512 + kt * 32 + quad * 8);
        short8 B1 = *(const short8*)(wfc + (size_t)(16 + col) * 512 + kt * 32 + quad * 8);
        C0 = __builtin_amdgcn_mfma_f32_16x16x32_bf16(A, B0, C0, 0, 0, 0);
        C1 = __builtin_amdgcn_mfma_f32_16x16x32_bf16(A, B1, C1, 0, 0, 0);
    }
    float b0 = bfc[col], b1 = bfc[16 + col];
    #pragma unroll
    for (int r = 0; r < 4; ++r) {
        int m = m0 + quad * 4 + r;
        sc[(size_t)m * 32 + col] = C0[r] + b0;
        sc[(size_t)m * 32 + 16 + col] = C1[r] + b1;
    }
}

// ---------------- CRF: true path score + forward algorithm, loss += total - true ----------------
// Double-buffered alpha: ONE barrier per t-step; sc/mask prefetched one step ahead.
__global__ __launch_bounds__(1024, 1) void k_crf(const float* __restrict__ sc, const int* __restrict__ tags,
                                                 const int* __restrict__ mask, const float* __restrict__ tr,
                                                 float* __restrict__ out) {
    __shared__ float Tm[32][33];
    __shared__ float al[2][32];
    __shared__ float trueb;
    const int b = blockIdx.x, tid = threadIdx.x;
    { int i = tid >> 5, j = tid & 31; Tm[i][j] = tr[tid]; }
    __syncthreads();
    if (tid < 64) {
        float acc = 0.f; int cnt = 0;
        for (int t = tid; t < 512; t += 64) cnt += mask[b * 512 + t];
        for (int t = tid + 1; t < 512; t += 64) {
            if (mask[b * 512 + t]) {
                int tg = tags[b * 512 + t], tp = tags[b * 512 + t - 1];
                acc += Tm[tp][tg] + sc[((size_t)t * 64 + b) * 32 + tg];
            }
        }
        #pragma unroll
        for (int m = 1; m < 64; m <<= 1) { acc += __shfl_xor(acc, m); cnt += __shfl_xor(cnt, m); }
        if (tid == 0) {
            int tg0 = tags[b * 512];
            float first = Tm[30][tg0] + sc[(size_t)b * 32 + tg0];
            int lt = tags[b * 512 + cnt - 1];
            trueb = first + acc + Tm[lt][31];
        }
    }
    if (tid < 32) al[0][tid] = Tm[30][tid] + sc[(size_t)b * 32 + tid];
    __syncthreads();
    const int j = tid >> 5, i = tid & 31;
    int cur = 0;
    float scn = sc[((size_t)64 + b) * 32 + j];
    int mkn = mask[b * 512 + 1];
    #pragma clang loop unroll(disable)
    for (int t = 1; t < 512; ++t) {
        float v = al[cur][i] + Tm[i][j];
        float mx = v;
        #pragma unroll
        for (int m = 1; m < 32; m <<= 1) mx = fmaxf(mx, __shfl_xor(mx, m));
        float e = __expf(v - mx);
        #pragma unroll
        for (int m = 1; m < 32; m <<= 1) e += __shfl_xor(e, m);
        float nv = mx + __logf(e) + scn;
        int mk = mkn;
        int tn = t < 511 ? t + 1 : 511;
        scn = sc[((size_t)tn * 64 + b) * 32 + j];
        mkn = mask[b * 512 + tn];
        if (i == 0) al[cur ^ 1][j] = mk ? nv : al[cur][j];
        __syncthreads();
        cur ^= 1;
    }
    if (tid < 32) {
        float v = al[cur][tid] + Tm[tid][31];
        float mx = v;
        #pragma unroll
        for (int m = 1; m < 32; m <<= 1) mx = fmaxf(mx, __shfl_xor(mx, m));
        float e = __expf(v - mx);
        #pragma unroll
        for (int m = 1; m < 32; m <<= 1) e += __shfl_xor(e, m);
        if (tid == 0) atomicAdd(out, mx + __logf(e) - trueb);
    }
}

extern "C" void kernel_launch(void* const* d_in, const int* in_sizes, int n_in,
                              void* d_out, int out_size, void* d_ws, size_t ws_size,
                              hipStream_t stream) {
    const int* x      = (const int*)d_in[0];
    const int* tags   = (const int*)d_in[1];
    const int* mask   = (const int*)d_in[2];
    const float* emb  = (const float*)d_in[3];
    const float* wihf = (const float*)d_in[4];
    const float* whhf = (const float*)d_in[5];
    const float* bf_  = (const float*)d_in[6];
    const float* wihb = (const float*)d_in[7];
    const float* whhb = (const float*)d_in[8];
    const float* bb_  = (const float*)d_in[9];
    const float* wfc  = (const float*)d_in[10];
    const float* bfc  = (const float*)d_in[11];
    const float* tr   = (const float*)d_in[12];

    char* ws = (char*)d_ws;
    unsigned short* et   = (unsigned short*)(ws);                 //  16,777,216 B
    unsigned short* wbf  = (unsigned short*)(ws + 16777216);      //   1,064,960 B (wih f|b cat, then wfc @ elem 524288)
    unsigned char*  w8   = (unsigned char*)(ws + 17842176);      //     524,288 B (whh f|b fp8)
    unsigned short* gx   = (unsigned short*)(ws + 18366464);      // 134,217,728 B
    unsigned short* hcat = (unsigned short*)(ws + 152584192);     //  33,554,432 B
    float* sc            = (float*)(ws + 186138624);              //   4,194,304 B

    hipMemsetAsync(d_out, 0, sizeof(float), stream);
    k_cast_weights<<<2080, 256, 0, stream>>>(wihf, wihb, wfc, wbf);
    k_cast_fp8<<<1024, 256, 0, stream>>>(whhf, whhb, w8);
    k_gather<<<4096, 256, 0, stream>>>(x, emb, et);
    dim3 g2(256, 16);
    k_gx<<<g2, 256, 0, stream>>>(et, wbf, bf_, bb_, gx);
    k_lstm<<<64, 512, 0, stream>>>(w8, gx, hcat);
    k_scores<<<512, 256, 0, stream>>>(hcat, wbf + 524288, bfc, sc);
    k_crf<<<64, 1024, 0, stream>>>(sc, tags, mask, tr, (float*)d_out);
}